// Round 3
// baseline (138.780 us; speedup 1.0000x reference)
//
#include <hip/hip_runtime.h>

// Problem constants (from reference)
#define VOCAB 50000
#define SEQ   2048
#define BATCH 64
#define DIM   256
#define H1    100
#define H2    150
#define HASH  4096            // per-row hash table (load factor <= 0.5)
#define NCH   8               // chunks per row
#define CHUNK (SEQ / NCH)     // 256
#define NT    1024
#define NWAVE (NT / 64)       // 16

// ---------------------------------------------------------------------------
// Kernel 0: per-row tf-idf scores. 64 blocks = 1 row each. Builds the row
// histogram once, writes (emb_float4_offset = tok*64, score) pairs transposed
// so the gather kernel reads them coalesced and needs NO 64-bit multiply.
// ---------------------------------------------------------------------------
__global__ __launch_bounds__(1024)
void k_scores(const int* __restrict__ x,
              const float* __restrict__ idf,
              int2* __restrict__ pairs) {    // [BATCH][SEQ] (tok<<6, score bits)
    __shared__ int tok[SEQ];       //  8 KB
    __shared__ int hkey[HASH];     // 16 KB
    __shared__ int hcnt[HASH];     // 16 KB
    const int r = blockIdx.x;      // batch row
    const int t = threadIdx.x;

    for (int i = t; i < HASH; i += NT) { hkey[i] = -1; hcnt[i] = 0; }
#pragma unroll
    for (int n = 0; n < SEQ / NT; ++n) {
        const int s = n * NT + t;
        tok[s] = x[s * BATCH + r];
    }
    __syncthreads();

#pragma unroll
    for (int n = 0; n < SEQ / NT; ++n) {
        const int s = n * NT + t;
        const int mytok = tok[s];
        unsigned h = ((unsigned)mytok * 2654435761u) >> 20;   // top 12 bits
        while (true) {
            int prev = atomicCAS(&hkey[h], -1, mytok);        // LDS-local
            if (prev == -1 || prev == mytok) { atomicAdd(&hcnt[h], 1); break; }
            h = (h + 1) & (HASH - 1);
        }
    }
    __syncthreads();

#pragma unroll
    for (int n = 0; n < SEQ / NT; ++n) {
        const int s = n * NT + t;
        const int mytok = tok[s];
        unsigned h = ((unsigned)mytok * 2654435761u) >> 20;
        while (hkey[h] != mytok) h = (h + 1) & (HASH - 1);
        const float sc = (mytok == 0) ? 0.0f : (float)hcnt[h] * idf[mytok];
        pairs[(size_t)r * SEQ + s] = make_int2(mytok << 6, __float_as_int(sc));
    }
}

// ---------------------------------------------------------------------------
// Kernel 1: pure gather-pool, 512 blocks, PLUS an attribution probe:
// a second cache-hot gather pass whose result is kept alive via asm (dead
// otherwise). Opaque-address asm barrier defeats load-CSE with pass 1.
// Purpose: (1) marginal cost of a hot gather pass = Δdur vs R1's 127.8;
// (2) pushes this dispatch above the ~42us top-5 cutoff created by the
// harness's 256MiB fillBufferAligned poisons, so we FINALLY get counters
// (FETCH_SIZE / VALUBusy / Occupancy) for our own code. Probe is removed
// next round.
// ---------------------------------------------------------------------------
__global__ __launch_bounds__(1024)
void k_gather(const int2* __restrict__ pairs,
              const float* __restrict__ emb,
              float* __restrict__ partials) {    // [BATCH*NCH][DIM]
    __shared__ int   coff[CHUNK];        //  1 KB  (float4-index = tok*64)
    __shared__ float csc[CHUNK];         //  1 KB
    __shared__ float wacc[NWAVE][DIM];   // 16 KB

    const int bx = blockIdx.x;          // 0..511
    const int r  = bx >> 3;             // batch row
    const int c  = bx & (NCH - 1);      // chunk
    const int t  = threadIdx.x;         // 0..1023
    const int w  = t >> 6, lane = t & 63;

    if (t < CHUNK) {
        const int2 p = pairs[(size_t)r * SEQ + c * CHUNK + t];
        coff[t] = p.x;                  // tok*64, fits int (max 3.2M)
        csc[t]  = __int_as_float(p.y);
    }
    __syncthreads();

    const float4* embv = (const float4*)emb;   // emb row = 64 float4
    const int i0 = w * (CHUNK / NWAVE);

    // ---- pass 1 (real): cold gather-pool ----
    {
        float4 acc = make_float4(0.f, 0.f, 0.f, 0.f);
#pragma unroll
        for (int i = 0; i < CHUNK / NWAVE; ++i) {
            const float sv = csc[i0 + i];          // LDS broadcast
            const float4 v = embv[(unsigned)(coff[i0 + i] + lane)];
            acc.x = fmaf(v.x, sv, acc.x);
            acc.y = fmaf(v.y, sv, acc.y);
            acc.z = fmaf(v.z, sv, acc.z);
            acc.w = fmaf(v.w, sv, acc.w);
        }
        ((float4*)wacc[w])[lane] = acc;
    }

    // ---- pass 2 (probe): identical addresses, cache-hot, result discarded ----
    {
        float4 acc2 = make_float4(0.f, 0.f, 0.f, 0.f);
#pragma unroll
        for (int i = 0; i < CHUNK / NWAVE; ++i) {
            const float sv = csc[i0 + i];
            int idx = coff[i0 + i] + lane;
            asm volatile("" : "+v"(idx));          // opaque: force real re-loads
            const float4 v = embv[(unsigned)idx];
            acc2.x = fmaf(v.x, sv, acc2.x);
            acc2.y = fmaf(v.y, sv, acc2.y);
            acc2.z = fmaf(v.z, sv, acc2.z);
            acc2.w = fmaf(v.w, sv, acc2.w);
        }
        asm volatile("" :: "v"(acc2.x), "v"(acc2.y), "v"(acc2.z), "v"(acc2.w));
    }
    __syncthreads();

    // reduce waves -> chunk partial (coalesced 1 KB write)
    if (t < DIM) {
        float a = 0.0f;
#pragma unroll
        for (int i = 0; i < NWAVE; ++i) a += wacc[i][t];
        partials[(size_t)bx * DIM + t] = a;
    }
}

// ---------------------------------------------------------------------------
// Kernel 2: per-row partial reduce + 3-layer MLP + softmax (proven tail).
// ---------------------------------------------------------------------------
__global__ __launch_bounds__(1024)
void k_mlp(const float* __restrict__ partials,
           const float* __restrict__ W1, const float* __restrict__ b1,
           const float* __restrict__ W2, const float* __restrict__ b2,
           const float* __restrict__ W3, const float* __restrict__ b3,
           float* __restrict__ out) {
    __shared__ float pooled[DIM];
    __shared__ float hp1[128][4];
    __shared__ float h1s[112];
    __shared__ float hp2[H2][4];
    __shared__ float h2s[152];
    __shared__ float lg[2];
    const int r = blockIdx.x;
    const int t = threadIdx.x;

    if (t < DIM) {
        float a = 0.0f;
#pragma unroll
        for (int cc = 0; cc < NCH; ++cc)
            a += partials[((size_t)r * NCH + cc) * DIM + t];
        pooled[t] = a;
    }
    __syncthreads();

    if (t < 512) {
        const int j = t >> 2;            // 0..127 (j<100 active)
        const int q = t & 3;             // k-quarter
        if (j < H1) {
            const float4* wv = (const float4*)(W1 + j * DIM + q * 64);
            const float4* pv = ((const float4*)pooled) + q * 16;
            float a = 0.0f;
#pragma unroll
            for (int i = 0; i < 16; ++i) {
                const float4 ww = wv[i];
                const float4 pp = pv[i];
                a += ww.x * pp.x + ww.y * pp.y + ww.z * pp.z + ww.w * pp.w;
            }
            hp1[j][q] = a;
        }
    }
    __syncthreads();
    if (t < H1)
        h1s[t] = fmaxf(hp1[t][0] + hp1[t][1] + hp1[t][2] + hp1[t][3] + b1[t], 0.0f);
    __syncthreads();

    if (t < 600) {
        const int j = t >> 2;            // 0..149
        const int q = t & 3;             // k-chunk of 25
        const float* wv = W2 + j * H1 + q * 25;
        float a = 0.0f;
#pragma unroll
        for (int i = 0; i < 25; ++i)
            a = fmaf(wv[i], h1s[q * 25 + i], a);
        hp2[j][q] = a;
    }
    __syncthreads();
    if (t < H2)
        h2s[t] = fmaxf(hp2[t][0] + hp2[t][1] + hp2[t][2] + hp2[t][3] + b2[t], 0.0f);
    __syncthreads();

    if (t < 2) {
        const float* wv = W3 + t * H2;
        float a = b3[t];
        for (int k = 0; k < H2; ++k) a = fmaf(wv[k], h2s[k], a);
        lg[t] = a;
    }
    __syncthreads();
    if (t == 0) {
        const float m  = fmaxf(lg[0], lg[1]);
        const float e0 = __expf(lg[0] - m);
        const float e1 = __expf(lg[1] - m);
        const float inv = 1.0f / (e0 + e1);
        out[r * 2 + 0] = e0 * inv;
        out[r * 2 + 1] = e1 * inv;
    }
}

// ---------------------------------------------------------------------------
extern "C" void kernel_launch(void* const* d_in, const int* in_sizes, int n_in,
                              void* d_out, int out_size, void* d_ws, size_t ws_size,
                              hipStream_t stream) {
    const int*   x   = (const int*)  d_in[0];   // [SEQ, BATCH] int32
    const float* emb = (const float*)d_in[1];   // [VOCAB, DIM]
    const float* idf = (const float*)d_in[2];   // [VOCAB]
    const float* W1  = (const float*)d_in[3];   // [H1, DIM]
    const float* b1  = (const float*)d_in[4];   // [H1]
    const float* W2  = (const float*)d_in[5];   // [H2, H1]
    const float* b2  = (const float*)d_in[6];   // [H2]
    const float* W3  = (const float*)d_in[7];   // [2, H2]
    const float* b3  = (const float*)d_in[8];   // [2]
    float* out = (float*)d_out;                 // [BATCH, 2]

    int2*  pairs    = (int2*)d_ws;                          // [64][2048] = 1 MB
    float* partials = (float*)((char*)d_ws + (size_t)BATCH * SEQ * sizeof(int2));

    k_scores<<<BATCH, NT, 0, stream>>>(x, idf, pairs);
    k_gather<<<BATCH * NCH, NT, 0, stream>>>(pairs, emb, partials);
    k_mlp   <<<BATCH, NT, 0, stream>>>(partials, W1, b1, W2, b2, W3, b3, out);
}

// Round 4
// 127.336 us; speedup vs baseline: 1.0899x; 1.0899x over previous
//
#include <hip/hip_runtime.h>

// Problem constants (from reference)
#define VOCAB 50000
#define SEQ   2048
#define BATCH 64
#define DIM   256
#define H1    100
#define H2    150
#define HASH  4096            // per-row hash table (load factor <= 0.5)
#define NCH   8               // chunks per row
#define CHUNK (SEQ / NCH)     // 256
#define NT    1024
#define NWAVE (NT / 64)       // 16

// ---------------------------------------------------------------------------
// Kernel 1 (fused, proven-best structure @127.1us): 512 blocks = (row, chunk).
// Per block: full-row tf hash histogram in LDS (redundant x8 per row — PROVEN
// free: R1 removed 7/8 of it for +0.7us, since the redundancy is parallel
// across blocks, not serial), tf-idf scores for its 256-token chunk, emb
// gather-pool (float4, wave-coalesced 1KB rows), deterministic partials write.
//
// Attribution (R3 probe): a second cache-hot gather pass costs +10.9us total;
// single-pass gather ~12-16us = at its issue/BW floor (134MB logical traffic
// is compulsory: every (b,s) needs its full 1KB emb row, tokens ~distinct).
// ~100us of the 127.8 dur is harness-fixed (42us x 256MiB ws poison + reset
// dispatches, serialized on-stream). Remaining controllable headroom <10us.
//
// Micro-opt this round: 32-bit gather addressing (tok*64+lane < 2^22) —
// avoids 64-bit v_mad per emb load (16/lane x 131K waves).
// ---------------------------------------------------------------------------
__global__ __launch_bounds__(1024)
void k_gather(const int* __restrict__ x,
              const float* __restrict__ emb,
              const float* __restrict__ idf,
              float* __restrict__ partials) {    // [BATCH*NCH][DIM]
    __shared__ int   tok[SEQ];          //  8 KB
    __shared__ int   hkey[HASH];        // 16 KB
    __shared__ int   hcnt[HASH];        // 16 KB
    __shared__ float sc[CHUNK];         //  1 KB
    __shared__ float wacc[NWAVE][DIM];  // 16 KB

    const int bx = blockIdx.x;          // 0..511
    const int r  = bx >> 3;             // batch row
    const int c  = bx & (NCH - 1);      // chunk
    const int t  = threadIdx.x;         // 0..1023
    const int w  = t >> 6, lane = t & 63;
    const int s0 = c * CHUNK;

    // ---- row tokens + hash init ----
    for (int i = t; i < HASH; i += NT) { hkey[i] = -1; hcnt[i] = 0; }
#pragma unroll
    for (int n = 0; n < SEQ / NT; ++n) {
        const int s = n * NT + t;
        tok[s] = x[s * BATCH + r];
    }
    __syncthreads();

    // ---- tf histogram insert (full row; 2 tokens/thread, LDS-local) ----
#pragma unroll
    for (int n = 0; n < SEQ / NT; ++n) {
        const int s = n * NT + t;
        const int mytok = tok[s];
        unsigned h = ((unsigned)mytok * 2654435761u) >> 20;   // top 12 bits
        while (true) {
            int prev = atomicCAS(&hkey[h], -1, mytok);
            if (prev == -1 || prev == mytok) { atomicAdd(&hcnt[h], 1); break; }
            h = (h + 1) & (HASH - 1);
        }
    }
    __syncthreads();

    // ---- scores for this chunk only ----
    if (t < CHUNK) {
        const int s = s0 + t;
        const int mytok = tok[s];
        unsigned h = ((unsigned)mytok * 2654435761u) >> 20;
        while (hkey[h] != mytok) h = (h + 1) & (HASH - 1);
        sc[t] = (mytok == 0) ? 0.0f : (float)hcnt[h] * idf[mytok];
    }
    __syncthreads();

    // ---- gather-pool this chunk: wave w handles 16 s-positions ----
    {
        const float4* embv = (const float4*)emb;   // emb row = 64 float4
        float4 acc = make_float4(0.f, 0.f, 0.f, 0.f);
        const int i0 = w * (CHUNK / NWAVE);
#pragma unroll
        for (int i = 0; i < CHUNK / NWAVE; ++i) {
            const float sv = sc[i0 + i];           // LDS broadcast
            // 32-bit index: tok*64+lane <= 3.2M, fits u32 -> no 64-bit mul
            const unsigned idx = (unsigned)tok[s0 + i0 + i] * 64u + (unsigned)lane;
            const float4 v = embv[idx];
            acc.x = fmaf(v.x, sv, acc.x);
            acc.y = fmaf(v.y, sv, acc.y);
            acc.z = fmaf(v.z, sv, acc.z);
            acc.w = fmaf(v.w, sv, acc.w);
        }
        ((float4*)wacc[w])[lane] = acc;
    }
    __syncthreads();

    // ---- reduce waves -> chunk partial (coalesced 1 KB write) ----
    if (t < DIM) {
        float a = 0.0f;
#pragma unroll
        for (int i = 0; i < NWAVE; ++i) a += wacc[i][t];
        partials[(size_t)bx * DIM + t] = a;
    }
}

// ---------------------------------------------------------------------------
// Kernel 2: per-row partial reduce + 3-layer MLP + softmax (proven tail).
// 64 blocks x 1024 threads.
// ---------------------------------------------------------------------------
__global__ __launch_bounds__(1024)
void k_mlp(const float* __restrict__ partials,
           const float* __restrict__ W1, const float* __restrict__ b1,
           const float* __restrict__ W2, const float* __restrict__ b2,
           const float* __restrict__ W3, const float* __restrict__ b3,
           float* __restrict__ out) {
    __shared__ float pooled[DIM];
    __shared__ float hp1[128][4];
    __shared__ float h1s[112];
    __shared__ float hp2[H2][4];
    __shared__ float h2s[152];
    __shared__ float lg[2];
    const int r = blockIdx.x;
    const int t = threadIdx.x;

    if (t < DIM) {
        float a = 0.0f;
#pragma unroll
        for (int cc = 0; cc < NCH; ++cc)
            a += partials[((size_t)r * NCH + cc) * DIM + t];
        pooled[t] = a;
    }
    __syncthreads();

    // stage 1 (100 neurons, k=256): 4 threads/neuron
    if (t < 512) {
        const int j = t >> 2;            // 0..127 (j<100 active)
        const int q = t & 3;             // k-quarter
        if (j < H1) {
            const float4* wv = (const float4*)(W1 + j * DIM + q * 64);
            const float4* pv = ((const float4*)pooled) + q * 16;
            float a = 0.0f;
#pragma unroll
            for (int i = 0; i < 16; ++i) {
                const float4 ww = wv[i];
                const float4 pp = pv[i];
                a += ww.x * pp.x + ww.y * pp.y + ww.z * pp.z + ww.w * pp.w;
            }
            hp1[j][q] = a;
        }
    }
    __syncthreads();
    if (t < H1)
        h1s[t] = fmaxf(hp1[t][0] + hp1[t][1] + hp1[t][2] + hp1[t][3] + b1[t], 0.0f);
    __syncthreads();

    // stage 2 (150 neurons, k=100): 4 threads/neuron
    if (t < 600) {
        const int j = t >> 2;            // 0..149
        const int q = t & 3;             // k-chunk of 25
        const float* wv = W2 + j * H1 + q * 25;
        float a = 0.0f;
#pragma unroll
        for (int i = 0; i < 25; ++i)
            a = fmaf(wv[i], h1s[q * 25 + i], a);
        hp2[j][q] = a;
    }
    __syncthreads();
    if (t < H2)
        h2s[t] = fmaxf(hp2[t][0] + hp2[t][1] + hp2[t][2] + hp2[t][3] + b2[t], 0.0f);
    __syncthreads();

    // logits + softmax
    if (t < 2) {
        const float* wv = W3 + t * H2;
        float a = b3[t];
        for (int k = 0; k < H2; ++k) a = fmaf(wv[k], h2s[k], a);
        lg[t] = a;
    }
    __syncthreads();
    if (t == 0) {
        const float m  = fmaxf(lg[0], lg[1]);
        const float e0 = __expf(lg[0] - m);
        const float e1 = __expf(lg[1] - m);
        const float inv = 1.0f / (e0 + e1);
        out[r * 2 + 0] = e0 * inv;
        out[r * 2 + 1] = e1 * inv;
    }
}

// ---------------------------------------------------------------------------
extern "C" void kernel_launch(void* const* d_in, const int* in_sizes, int n_in,
                              void* d_out, int out_size, void* d_ws, size_t ws_size,
                              hipStream_t stream) {
    const int*   x   = (const int*)  d_in[0];   // [SEQ, BATCH] int32
    const float* emb = (const float*)d_in[1];   // [VOCAB, DIM]
    const float* idf = (const float*)d_in[2];   // [VOCAB]
    const float* W1  = (const float*)d_in[3];   // [H1, DIM]
    const float* b1  = (const float*)d_in[4];   // [H1]
    const float* W2  = (const float*)d_in[5];   // [H2, H1]
    const float* b2  = (const float*)d_in[6];   // [H2]
    const float* W3  = (const float*)d_in[7];   // [2, H2]
    const float* b3  = (const float*)d_in[8];   // [2]
    float* out = (float*)d_out;                 // [BATCH, 2]

    float* partials = (float*)d_ws;             // [512][256] = 512 KB

    k_gather<<<BATCH * NCH, NT, 0, stream>>>(x, emb, idf, partials);
    k_mlp   <<<BATCH, NT, 0, stream>>>(partials, W1, b1, W2, b2, W3, b3, out);
}